// Round 1
// baseline (390.252 us; speedup 1.0000x reference)
//
#include <hip/hip_runtime.h>

#define C 256
#define HW 4096

typedef __attribute__((ext_vector_type(8))) short short8;
typedef __attribute__((ext_vector_type(4))) float float4v;

__device__ __forceinline__ unsigned short f2bf(float x) {
    unsigned u = __builtin_bit_cast(unsigned, x);
    u = (u + 0x7fffu + ((u >> 16) & 1u)) >> 16;
    return (unsigned short)u;
}

// async global->LDS DMA: 64 lanes x 16B, LDS dst = base + lane*16
__device__ __forceinline__ void g2l_b128(const void* g, void* l) {
    __builtin_amdgcn_global_load_lds(
        (const __attribute__((address_space(1))) unsigned int*)g,
        (__attribute__((address_space(3))) unsigned int*)l, 16, 0, 0);
}

// Kernel 1: one block. g = IDFT(1/(1 - DFT(kernel))), then expanded A-fragment table:
// tab[(s*64 + lane)*8 + j] = bf16(gsh[(m - 16s - 8q - j) & 255]), m=lane&15, q=lane>>4.
// (Verified in earlier rounds; unchanged.)
__global__ void build_tab_kernel(const float* __restrict__ filt, unsigned short* __restrict__ tab) {
    __shared__ float twc[256], tws[256];
    __shared__ float Gre[256], Gim[256];
    __shared__ float gsh[256];
    const int t = threadIdx.x;
    const double PI = 3.14159265358979323846;
    double th = (double)t * (PI / 128.0);      // 2*pi*t/256
    twc[t] = (float)cos(th);
    tws[t] = (float)sin(th);
    __syncthreads();
    float re = 1.0f, im = 0.0f;
    for (int i = 0; i < 27; ++i) {
        int d = (243 + i) & 255;               // pad_roll layout offsets
        int idx = (t * d) & 255;
        float fv = filt[i];
        re -= fv * twc[idx];
        im += fv * tws[idx];
    }
    float den = re * re + im * im;
    Gre[t] = re / den;
    Gim[t] = -im / den;
    __syncthreads();
    float acc = 0.0f;
    for (int f = 0; f < 256; ++f) {
        int idx = (f * t) & 255;
        acc += Gre[f] * twc[idx] - Gim[f] * tws[idx];
    }
    gsh[t] = acc * (1.0f / 256.0f);
    __syncthreads();
    for (int e = t; e < 16 * 64 * 8; e += 256) {
        int j = e & 7;
        int lane = (e >> 3) & 63;
        int s = e >> 9;
        int mm = lane & 15, q = lane >> 4;
        int src = (mm - 16 * s - 8 * q - j) & 255;
        tab[e] = f2bf(gsh[src]);
    }
}

// ---- direct-from-global B fragments, barrier-free K-loop ----

// 8 k-strided dword loads: element j = act row (base_k + j), fixed pixel column.
__device__ __forceinline__ void load8(unsigned (&u)[8], const float* __restrict__ base) {
#pragma unroll
    for (int j = 0; j < 8; ++j)
        u[j] = __builtin_bit_cast(unsigned, base[j * HW]);
}

// One K-step ag (32 rows): pack fp32->bf16 (round-half-up via +0x8000, identical to
// the verified kernel), then 16 MFMAs covering all 256 output channels.
// sp = (2*AG - ct) & 15 is compile-time -> ds_read_b128 with immediate offsets.
template <int AG>
__device__ __forceinline__ void mfma_step(const unsigned (&u)[8],
                                          const unsigned short* afrags,
                                          int lane, float4v (&acc)[16]) {
    unsigned v[8];
#pragma unroll
    for (int j = 0; j < 8; ++j) v[j] = u[j] + 0x8000u;
    uint4 pk;
    pk.x = (v[0] >> 16) | (v[1] & 0xFFFF0000u);
    pk.y = (v[2] >> 16) | (v[3] & 0xFFFF0000u);
    pk.z = (v[4] >> 16) | (v[5] & 0xFFFF0000u);
    pk.w = (v[6] >> 16) | (v[7] & 0xFFFF0000u);
    const short8 bfr = __builtin_bit_cast(short8, pk);
#pragma unroll
    for (int ct = 0; ct < 16; ++ct) {
        const int sp = (2 * AG - ct) & 15;
        const short8 af = *(const short8*)&afrags[sp * 512 + lane * 8];
        acc[ct] = __builtin_amdgcn_mfma_f32_16x16x32_bf16(af, bfr, acc[ct], 0, 0, 0);
    }
}

// Kernel 2: out[c,p] = sum_k W[c,k]*act[k,p].
// Block: 256 c x 64 px tile. Wave w owns px sub-block [p0+16w, p0+16w+16) x all 256 c
// (px split across waves -> every act element is loaded by exactly one lane: no LDS
// staging, no chunk barriers). B frags load straight from global (triple-buffered,
// 2-step prefetch lead); A frags from a 16 KB LDS table (conflict-free b128 reads).
__global__ __launch_bounds__(256, 4)
void toeplitz_gemm_kernel(const float* __restrict__ act,
                          const unsigned short* __restrict__ tab,
                          float* __restrict__ out) {
    __shared__ unsigned short afrags[16 * 64 * 8];   // 16 KB

    const int tid = threadIdx.x;
    const int wave = tid >> 6;
    const int lane = tid & 63;
    const int m = lane & 15;        // MFMA col (B,D) = px within 16
    const int quad = lane >> 4;     // k-subchunk selector / D row group
    const int blk = blockIdx.x;
    const int n = blk >> 6;                 // 64 px-tiles per image
    const int p0 = (blk & 63) << 6;
    const float* __restrict__ actn = act + (size_t)n * (C * HW);
    float* __restrict__ outn = out + (size_t)n * (C * HW);

    // ---- A-fragment table: 16 KB global -> LDS, 16B/lane DMA ----
#pragma unroll
    for (int i = 0; i < 4; ++i) {
        const int seg = wave * 4 + i;                  // 16 segments of 1024 B
        g2l_b128(tab + seg * 512 + lane * 8, &afrags[seg * 512]);
    }

    // per-lane act column pointer: k = ag*32 + quad*8 + j, px = p0 + wave*16 + m
    const float* __restrict__ colp = actn + quad * 8 * HW + p0 + wave * 16 + m;

    unsigned u0[8], u1[8], u2[8];
    load8(u0, colp);                 // ag 0 (in flight across the tab barrier)
    load8(u1, colp + 1 * 32 * HW);   // ag 1

    __syncthreads();                 // afrags ready (drains tab DMA + early loads)

    float4v acc[16];
#pragma unroll
    for (int ct = 0; ct < 16; ++ct) acc[ct] = (float4v){0.f, 0.f, 0.f, 0.f};

    // barrier-free pipelined K-loop: loads lead compute by 2 steps
    load8(u2, colp + 2 * 32 * HW);
    mfma_step<0>(u0, afrags, lane, acc);
    load8(u0, colp + 3 * 32 * HW);
    mfma_step<1>(u1, afrags, lane, acc);
    load8(u1, colp + 4 * 32 * HW);
    mfma_step<2>(u2, afrags, lane, acc);
    load8(u2, colp + 5 * 32 * HW);
    mfma_step<3>(u0, afrags, lane, acc);
    load8(u0, colp + 6 * 32 * HW);
    mfma_step<4>(u1, afrags, lane, acc);
    load8(u1, colp + 7 * 32 * HW);
    mfma_step<5>(u2, afrags, lane, acc);
    mfma_step<6>(u0, afrags, lane, acc);
    mfma_step<7>(u1, afrags, lane, acc);

    // ---- epilogue: D layout col=lane&15, row=quad*4+r; c = ct*16 + quad*4 + r ----
#pragma unroll
    for (int ct = 0; ct < 16; ++ct) {
#pragma unroll
        for (int r = 0; r < 4; ++r) {
            const int cc = ct * 16 + quad * 4 + r;
            outn[(size_t)cc * HW + p0 + wave * 16 + m] = acc[ct][r];
        }
    }
}

extern "C" void kernel_launch(void* const* d_in, const int* in_sizes, int n_in,
                              void* d_out, int out_size, void* d_ws, size_t ws_size,
                              hipStream_t stream) {
    const float* act = (const float*)d_in[0];
    const float* filt = (const float*)d_in[1];
    float* out = (float*)d_out;
    unsigned short* tab = (unsigned short*)d_ws;   // 16384 bytes used

    build_tab_kernel<<<1, 256, 0, stream>>>(filt, tab);
    toeplitz_gemm_kernel<<<2048, 256, 0, stream>>>(act, tab, out);
}

// Round 4
// 250.719 us; speedup vs baseline: 1.5565x; 1.5565x over previous
//
#include <hip/hip_runtime.h>

#define C 256
#define HW 4096
#define STRIDE 66     // dwords per act row in LDS (64 px + 2 pad) -> 2-way-free bank pattern
#define CHROWS 32     // rows per K-chunk
#define NCHUNK 8
#define NBUF 4

typedef __attribute__((ext_vector_type(8))) short short8;
typedef __attribute__((ext_vector_type(4))) float float4v;

__device__ __forceinline__ unsigned short f2bf(float x) {
    unsigned u = __builtin_bit_cast(unsigned, x);
    u = (u + 0x7fffu + ((u >> 16) & 1u)) >> 16;
    return (unsigned short)u;
}

// async global->LDS DMA: 64 lanes x 4B, LDS dst = wave-uniform base + lane*4 (256 B/instr, full lines)
__device__ __forceinline__ void g2l_b32(const void* g, void* l) {
    __builtin_amdgcn_global_load_lds(
        (const __attribute__((address_space(1))) unsigned int*)g,
        (__attribute__((address_space(3))) unsigned int*)l, 4, 0, 0);
}
// async global->LDS DMA: 64 lanes x 16B
__device__ __forceinline__ void g2l_b128(const void* g, void* l) {
    __builtin_amdgcn_global_load_lds(
        (const __attribute__((address_space(1))) unsigned int*)g,
        (__attribute__((address_space(3))) unsigned int*)l, 16, 0, 0);
}

template <int N>
__device__ __forceinline__ void wait_vmcnt() {
    asm volatile("s_waitcnt vmcnt(%0)" :: "n"(N) : "memory");
    __builtin_amdgcn_sched_barrier(0);   // rule #18: pin -- nothing crosses the counted wait
}

// Kernel 1: one block. g = IDFT(1/(1 - DFT(kernel))), then expanded A-fragment table:
// tab[(s*64 + lane)*8 + j] = bf16(gsh[(m - 16s - 8q - j) & 255]), m=lane&15, q=lane>>4.
// (Byte-identical to the verified round-0 kernel.)
__global__ void build_tab_kernel(const float* __restrict__ filt, unsigned short* __restrict__ tab) {
    __shared__ float twc[256], tws[256];
    __shared__ float Gre[256], Gim[256];
    __shared__ float gsh[256];
    const int t = threadIdx.x;
    const double PI = 3.14159265358979323846;
    double th = (double)t * (PI / 128.0);      // 2*pi*t/256
    twc[t] = (float)cos(th);
    tws[t] = (float)sin(th);
    __syncthreads();
    float re = 1.0f, im = 0.0f;
    for (int i = 0; i < 27; ++i) {
        int d = (243 + i) & 255;               // pad_roll layout offsets
        int idx = (t * d) & 255;
        float fv = filt[i];
        re -= fv * twc[idx];
        im += fv * tws[idx];
    }
    float den = re * re + im * im;
    Gre[t] = re / den;
    Gim[t] = -im / den;
    __syncthreads();
    float acc = 0.0f;
    for (int f = 0; f < 256; ++f) {
        int idx = (f * t) & 255;
        acc += Gre[f] * twc[idx] - Gim[f] * tws[idx];
    }
    gsh[t] = acc * (1.0f / 256.0f);
    __syncthreads();
    for (int e = t; e < 16 * 64 * 8; e += 256) {
        int j = e & 7;
        int lane = (e >> 3) & 63;
        int s = e >> 9;
        int mm = lane & 15, q = lane >> 4;
        int src = (mm - 16 * s - 8 * q - j) & 255;
        tab[e] = f2bf(gsh[src]);
    }
}

// Kernel 2: out[c,p] = sum_k W[c,k]*act[k,p].
// Block: 256 c x 64 px tile (round-0 decomposition: full-line 256-B DMA reads, full-line
// writes). K pipelined in 8 chunks of 32 rows, 4 LDS buffers, prefetch depth 2-3, counted
// s_waitcnt vmcnt(N) + raw s_barrier -- prefetch DMAs stay in flight across barriers
// (never drained to 0 until the tail), removing the round-0 per-chunk drain stall.
__global__ __launch_bounds__(256, 3)
void toeplitz_gemm_kernel(const float* __restrict__ act,
                          const unsigned short* __restrict__ tab,
                          float* __restrict__ out) {
    __shared__ float chunkbuf[NBUF][CHROWS * STRIDE];     // 4 x 8448 B = 33792 B
    __shared__ unsigned short afrags[16 * 64 * 8];        // 16384 B  (total 50176 -> 3 blocks/CU)

    const int tid = threadIdx.x;
    const int wave = tid >> 6;
    const int lane = tid & 63;
    const int m = lane & 15;        // MFMA row (A) / col (B,D)
    const int quad = lane >> 4;     // k-subchunk selector
    const int blk = blockIdx.x;
    const int n = blk >> 6;                 // 64 px-tiles per image
    const int p0 = (blk & 63) << 6;
    const float* __restrict__ actn = act + (size_t)n * (C * HW);
    float* __restrict__ outn = out + (size_t)n * (C * HW);

    // ---- A-fragment table: 16 KB global -> LDS, 16B/lane DMA (4 ops/wave) ----
#pragma unroll
    for (int i = 0; i < 4; ++i) {
        const int seg = wave * 4 + i;                      // 16 segments of 1024 B
        g2l_b128(tab + seg * 512 + lane * 8, &afrags[seg * 512]);
    }

    // issue one 32-row chunk (8 full-line DMAs per wave)
    auto issue = [&](int ch) {
        const float* src = actn + (size_t)(ch * CHROWS + wave * 8) * HW + p0 + lane;
#pragma unroll
        for (int i = 0; i < 8; ++i)
            g2l_b32(src + (size_t)i * HW, &chunkbuf[ch & (NBUF - 1)][(wave * 8 + i) * STRIDE]);
    };

    issue(0); issue(1); issue(2);            // prologue: depth-3 in flight (+afrags)

    float4v acc[4][4];
#pragma unroll
    for (int ct = 0; ct < 4; ++ct)
#pragma unroll
        for (int pt = 0; pt < 4; ++pt)
            acc[ct][pt] = (float4v){0.f, 0.f, 0.f, 0.f};

    // Phase c: wait own chunk-c DMAs retired (<=16 outstanding keeps c+1,c+2 flying),
    // barrier makes all waves' chunk-c rows visible, then issue c+3 (its buffer was
    // last read in phase c-1, so the phase-c barrier proves it is free), then compute.
#define PHASE(c, WN)                                                              \
    {                                                                             \
        wait_vmcnt<WN>();                                                         \
        __builtin_amdgcn_s_barrier();                                             \
        __builtin_amdgcn_sched_barrier(0);                                        \
        asm volatile("" ::: "memory");                                            \
        if ((c) + 3 < NCHUNK) issue((c) + 3);                                     \
        const float* cb = &chunkbuf[(c) & (NBUF - 1)][0];                         \
        short8 bfr[4];                                                            \
        _Pragma("unroll")                                                         \
        for (int pt = 0; pt < 4; ++pt) {                                          \
            const float* base = cb + (quad * 8) * STRIDE + pt * 16 + m;           \
            unsigned u[8];                                                        \
            _Pragma("unroll")                                                     \
            for (int j = 0; j < 8; ++j)                                           \
                u[j] = __builtin_bit_cast(unsigned, base[j * STRIDE]) + 0x8000u;  \
            uint4 pk;                                                             \
            pk.x = (u[0] >> 16) | (u[1] & 0xFFFF0000u);                           \
            pk.y = (u[2] >> 16) | (u[3] & 0xFFFF0000u);                           \
            pk.z = (u[4] >> 16) | (u[5] & 0xFFFF0000u);                           \
            pk.w = (u[6] >> 16) | (u[7] & 0xFFFF0000u);                           \
            bfr[pt] = __builtin_bit_cast(short8, pk);                             \
        }                                                                         \
        _Pragma("unroll")                                                         \
        for (int ct = 0; ct < 4; ++ct) {                                          \
            const int sp = (2 * (c) - ct - 4 * wave) & 15;                        \
            const short8 af = *(const short8*)&afrags[sp * 512 + lane * 8];       \
            _Pragma("unroll")                                                     \
            for (int pt = 0; pt < 4; ++pt)                                        \
                acc[ct][pt] = __builtin_amdgcn_mfma_f32_16x16x32_bf16(            \
                    af, bfr[pt], acc[ct][pt], 0, 0, 0);                           \
        }                                                                         \
    }

    PHASE(0, 16)   // retires afrags + chunk0; chunks 1,2 stay in flight
    PHASE(1, 16)
    PHASE(2, 16)
    PHASE(3, 16)
    PHASE(4, 16)
    PHASE(5, 16)   // outstanding 6,7
    PHASE(6, 8)
    PHASE(7, 0)
#undef PHASE

    // ---- epilogue (verified rounds 0-2): D layout col=lane&15, row=quad*4+r ----
#pragma unroll
    for (int ct = 0; ct < 4; ++ct) {
#pragma unroll
        for (int r = 0; r < 4; ++r) {
            const int cc = wave * 64 + ct * 16 + quad * 4 + r;
            float* op = outn + (size_t)cc * HW + p0;
#pragma unroll
            for (int pt = 0; pt < 4; ++pt) {
                op[pt * 16 + m] = acc[ct][pt][r];
            }
        }
    }
}

extern "C" void kernel_launch(void* const* d_in, const int* in_sizes, int n_in,
                              void* d_out, int out_size, void* d_ws, size_t ws_size,
                              hipStream_t stream) {
    const float* act = (const float*)d_in[0];
    const float* filt = (const float*)d_in[1];
    float* out = (float*)d_out;
    unsigned short* tab = (unsigned short*)d_ws;   // 16384 bytes used

    build_tab_kernel<<<1, 256, 0, stream>>>(filt, tab);
    toeplitz_gemm_kernel<<<2048, 256, 0, stream>>>(act, tab, out);
}